// Round 1
// baseline (672.023 us; speedup 1.0000x reference)
//
#include <hip/hip_runtime.h>
#include <hip/hip_bf16.h>

#define TOKENS 8192
#define IN_F   4096
#define OUT_F  4096

typedef __attribute__((ext_vector_type(8))) short bf16x8;   // 8 bf16 = 4 VGPRs
typedef __attribute__((ext_vector_type(4))) float f32x4;

static __device__ __forceinline__ unsigned short f2bf(float f) {
    union { float f; unsigned int u; } v;
    v.f = f;
    // round-to-nearest-even
    unsigned int r = v.u + 0x7fffu + ((v.u >> 16) & 1u);
    return (unsigned short)(r >> 16);
}

static __device__ __forceinline__ float softplus(float x) {
    return log1pf(__expf(x));   // rho ~ N(-4.6,1): no overflow risk
}

// ---- prep: W = mu + softplus(rho)*eps, cast to bf16. 4 elems/thread, float4 loads.
__global__ void prep_w_kernel(const float* __restrict__ mu,
                              const float* __restrict__ rho,
                              const float* __restrict__ eps,
                              __hip_bfloat16* __restrict__ w) {
    int i = blockIdx.x * 256 + threadIdx.x;          // group-of-4 index
    float4 m4 = ((const float4*)mu)[i];
    float4 r4 = ((const float4*)rho)[i];
    float4 e4 = ((const float4*)eps)[i];
    ushort4 o;
    o.x = f2bf(m4.x + softplus(r4.x) * e4.x);
    o.y = f2bf(m4.y + softplus(r4.y) * e4.y);
    o.z = f2bf(m4.z + softplus(r4.z) * e4.z);
    o.w = f2bf(m4.w + softplus(r4.w) * e4.w);
    ((ushort4*)w)[i] = o;
}

// ---- prep: x fp32 -> bf16
__global__ void conv_x_kernel(const float* __restrict__ x,
                              __hip_bfloat16* __restrict__ xb) {
    int i = blockIdx.x * 256 + threadIdx.x;
    float4 v = ((const float4*)x)[i];
    ushort4 o;
    o.x = f2bf(v.x); o.y = f2bf(v.y); o.z = f2bf(v.z); o.w = f2bf(v.w);
    ((ushort4*)xb)[i] = o;
}

// ---- prep: bias (fp32, stays fp32)
__global__ void prep_b_kernel(const float* __restrict__ bmu,
                              const float* __restrict__ brho,
                              const float* __restrict__ beps,
                              float* __restrict__ b) {
    int i = blockIdx.x * 256 + threadIdx.x;
    b[i] = bmu[i] + softplus(brho[i]) * beps[i];
}

// ---- GEMM: C[t,o] = sum_k Xb[t,k]*Wb[o,k] + bias[o]
// 128x128 tile, BK=32, 4 waves each computing 64x64 via 4x4 MFMA 16x16x32 tiles.
// global_load_lds width=16 staging, unpadded LDS (lane-contiguous order).
__global__ __launch_bounds__(256) void gemm_bt_kernel(
        const __hip_bfloat16* __restrict__ Xb,   // [TOKENS, IN_F]
        const __hip_bfloat16* __restrict__ Wb,   // [OUT_F, IN_F]
        const float* __restrict__ bias,          // [OUT_F]
        float* __restrict__ C) {                 // [TOKENS, OUT_F]
    __shared__ __hip_bfloat16 lds_a[128 * 32];
    __shared__ __hip_bfloat16 lds_b[128 * 32];

    const int tid  = threadIdx.x;
    const int lane = tid & 63;
    const int wave = tid >> 6;
    const int K    = IN_F;

    const int rowBase = blockIdx.y * 128;   // token dim
    const int colBase = blockIdx.x * 128;   // out-feature dim

    // staging: thread t -> row t/4 (0..63), 16B chunk t%4; issue1 adds 64 rows
    const int srow   = tid >> 2;
    const int schunk = tid & 3;
    const __hip_bfloat16* gA0 = Xb + (size_t)(rowBase + srow) * K + schunk * 8;
    const __hip_bfloat16* gA1 = gA0 + (size_t)64 * K;
    const __hip_bfloat16* gB0 = Wb + (size_t)(colBase + srow) * K + schunk * 8;
    const __hip_bfloat16* gB1 = gB0 + (size_t)64 * K;

    // per-lane LDS dest = wave-uniform base + lane*16B (unpadded, contiguous)
    __hip_bfloat16* lA0 = &lds_a[wave * 512 + lane * 8];
    __hip_bfloat16* lA1 = lA0 + 2048;
    __hip_bfloat16* lB0 = &lds_b[wave * 512 + lane * 8];
    __hip_bfloat16* lB1 = lB0 + 2048;

    f32x4 acc[4][4];
#pragma unroll
    for (int i = 0; i < 4; ++i)
#pragma unroll
        for (int j = 0; j < 4; ++j) acc[i][j] = (f32x4){0.f, 0.f, 0.f, 0.f};

    const int wm   = (wave >> 1) * 64;   // wave's 64x64 quadrant
    const int wn   = (wave & 1) * 64;
    const int fr   = lane & 15;          // fragment m/n index
    const int quad = lane >> 4;          // k-slice selector (A/B), row-group (C)

    for (int k0 = 0; k0 < K; k0 += 32) {
        __syncthreads();   // previous iter's ds_reads done before overwrite
        __builtin_amdgcn_global_load_lds(
            (const __attribute__((address_space(1))) void*)(gA0 + k0),
            (__attribute__((address_space(3))) void*)lA0, 16, 0, 0);
        __builtin_amdgcn_global_load_lds(
            (const __attribute__((address_space(1))) void*)(gA1 + k0),
            (__attribute__((address_space(3))) void*)lA1, 16, 0, 0);
        __builtin_amdgcn_global_load_lds(
            (const __attribute__((address_space(1))) void*)(gB0 + k0),
            (__attribute__((address_space(3))) void*)lB0, 16, 0, 0);
        __builtin_amdgcn_global_load_lds(
            (const __attribute__((address_space(1))) void*)(gB1 + k0),
            (__attribute__((address_space(3))) void*)lB1, 16, 0, 0);
        __syncthreads();   // compiler drains vmcnt before s_barrier

        bf16x8 af[4], bfr[4];
#pragma unroll
        for (int mt = 0; mt < 4; ++mt)
            af[mt] = *(const bf16x8*)&lds_a[(wm + mt * 16 + fr) * 32 + quad * 8];
#pragma unroll
        for (int nt = 0; nt < 4; ++nt)
            bfr[nt] = *(const bf16x8*)&lds_b[(wn + nt * 16 + fr) * 32 + quad * 8];

#pragma unroll
        for (int mt = 0; mt < 4; ++mt)
#pragma unroll
            for (int nt = 0; nt < 4; ++nt)
                acc[mt][nt] = __builtin_amdgcn_mfma_f32_16x16x32_bf16(
                    af[mt], bfr[nt], acc[mt][nt], 0, 0, 0);
    }

    // epilogue: C/D layout col=lane&15, row=quad*4+reg
#pragma unroll
    for (int nt = 0; nt < 4; ++nt) {
        const int col = colBase + wn + nt * 16 + fr;
        const float bv = bias[col];
#pragma unroll
        for (int mt = 0; mt < 4; ++mt) {
            const int row = rowBase + wm + mt * 16 + quad * 4;
#pragma unroll
            for (int r = 0; r < 4; ++r)
                C[(size_t)(row + r) * OUT_F + col] = acc[mt][nt][r] + bv;
        }
    }
}

extern "C" void kernel_launch(void* const* d_in, const int* in_sizes, int n_in,
                              void* d_out, int out_size, void* d_ws, size_t ws_size,
                              hipStream_t stream) {
    const float* x    = (const float*)d_in[0];
    const float* wmu  = (const float*)d_in[1];
    const float* wrho = (const float*)d_in[2];
    const float* bmu  = (const float*)d_in[3];
    const float* brho = (const float*)d_in[4];
    const float* epsw = (const float*)d_in[5];
    const float* epsb = (const float*)d_in[6];
    float* out = (float*)d_out;

    // workspace layout: x_bf16 (67108864 B) | w_bf16 (33554432 B) | bias (16384 B)
    char* ws = (char*)d_ws;
    __hip_bfloat16* xb = (__hip_bfloat16*)ws;
    __hip_bfloat16* wb = (__hip_bfloat16*)(ws + (size_t)TOKENS * IN_F * 2);
    float* bias = (float*)(ws + (size_t)TOKENS * IN_F * 2 + (size_t)OUT_F * IN_F * 2);

    conv_x_kernel<<<(TOKENS * IN_F) / 4 / 256, 256, 0, stream>>>(x, xb);
    prep_w_kernel<<<(OUT_F * IN_F) / 4 / 256, 256, 0, stream>>>(wmu, wrho, epsw, wb);
    prep_b_kernel<<<OUT_F / 256, 256, 0, stream>>>(bmu, brho, epsb, bias);

    dim3 grid(OUT_F / 128, TOKENS / 128);   // (32, 64)
    gemm_bt_kernel<<<grid, 256, 0, stream>>>(xb, wb, bias, out);
}